// Round 1
// baseline (896.094 us; speedup 1.0000x reference)
//
#include <hip/hip_runtime.h>

#define NN 100000
#define NE 1600000
#define FEAT 128

// ---------------- CSR build ----------------

__global__ void k_zero(int* __restrict__ deg) {
  int i = blockIdx.x * blockDim.x + threadIdx.x;
  if (i < NN) deg[i] = 0;
}

__global__ void k_count(const int* __restrict__ dst, int* __restrict__ deg) {
  int e = blockIdx.x * blockDim.x + threadIdx.x;
  if (e < NE) atomicAdd(&deg[dst[e]], 1);
}

// per-chunk sums (chunk = 1024 = 256 threads x 4)
__global__ void k_scan1(const int* __restrict__ deg, int* __restrict__ bsum) {
  __shared__ int red[4];
  int b = blockIdx.x, t = threadIdx.x;
  int s = 0;
  for (int j = 0; j < 4; ++j) {
    int i = b * 1024 + t + 256 * j;
    if (i < NN) s += deg[i];
  }
  for (int o = 32; o > 0; o >>= 1) s += __shfl_down(s, o, 64);
  if ((t & 63) == 0) red[t >> 6] = s;
  __syncthreads();
  if (t == 0) bsum[b] = red[0] + red[1] + red[2] + red[3];
}

__global__ void k_scan2(const int* __restrict__ bsum, int* __restrict__ bpref, int nb) {
  if (threadIdx.x == 0) {
    int run = 0;
    for (int b = 0; b < nb; ++b) { bpref[b] = run; run += bsum[b]; }
  }
}

__global__ void k_scan3(const int* __restrict__ deg, const int* __restrict__ bpref,
                        int* __restrict__ off, int* __restrict__ cur) {
  __shared__ int sc[256];
  int b = blockIdx.x, t = threadIdx.x;
  int base = b * 1024 + t * 4;
  int d[4]; int s = 0;
  for (int j = 0; j < 4; ++j) {
    int i = base + j;
    d[j] = (i < NN) ? deg[i] : 0;
    s += d[j];
  }
  sc[t] = s;
  __syncthreads();
  for (int o = 1; o < 256; o <<= 1) {
    int v = (t >= o) ? sc[t - o] : 0;
    __syncthreads();
    sc[t] += v;
    __syncthreads();
  }
  int run = bpref[b] + sc[t] - s;   // exclusive prefix for this thread's 4 elems
  for (int j = 0; j < 4; ++j) {
    int i = base + j;
    if (i < NN) { off[i] = run; cur[i] = run; }
    run += d[j];
  }
}

__global__ void k_fill(const int* __restrict__ src, const int* __restrict__ dst,
                       int* __restrict__ cur, int* __restrict__ csr) {
  int e = blockIdx.x * blockDim.x + threadIdx.x;
  if (e < NE) {
    int pos = atomicAdd(&cur[dst[e]], 1);
    csr[pos] = src[e];
  }
}

// ---------------- layer-1 mean aggregation ----------------
// one block (128 threads) per node; coalesced 512B row reads from L3
__global__ void k_agg1(const float* __restrict__ x, const int* __restrict__ csr,
                       const int* __restrict__ off, const int* __restrict__ deg,
                       float* __restrict__ agg) {
  int i = blockIdx.x;
  int t = threadIdx.x;
  int cnt = deg[i], st = off[i];
  float acc = 0.f;
  for (int e = 0; e < cnt; ++e) {
    int s = csr[st + e];
    acc += x[s * FEAT + t];
  }
  float inv = 1.f / (float)max(cnt, 1);
  agg[i * FEAT + t] = acc * inv;
}

// ---------------- fused GEMM: h1 = relu([agg|x] @ [W1l|W1r]^T + b1);
//                  p = h1@W2l^T, r = h1@W2r^T  (h1 never leaves LDS) -------
__global__ __launch_bounds__(256) void k_gemm1(
    const float* __restrict__ agg, const float* __restrict__ x,
    const float* __restrict__ W1l, const float* __restrict__ W1r,
    const float* __restrict__ b1,
    const float* __restrict__ W2l, const float* __restrict__ W2r,
    float* __restrict__ p, float* __restrict__ r) {
  __shared__ float As[64][17];    // 64 nodes x 16 k
  __shared__ float Bs[16][128];   // 16 k x 128 out
  __shared__ float hs[64][129];   // h1 tile
  int t = threadIdx.x;
  int node0 = blockIdx.x * 64;
  int tx = t & 15, ty = t >> 4;
  float acc[4][8];
#pragma unroll
  for (int a = 0; a < 4; ++a)
#pragma unroll
    for (int b = 0; b < 8; ++b) acc[a][b] = 0.f;

  for (int kc = 0; kc < 256; kc += 16) {
#pragma unroll
    for (int j = 0; j < 4; ++j) {
      int idx = t + 256 * j;
      int nn = idx >> 4, kk = idx & 15;
      int row = node0 + nn, kg = kc + kk;
      float v = 0.f;
      if (row < NN)
        v = (kg < 128) ? agg[row * 128 + kg] : x[row * 128 + (kg - 128)];
      As[nn][kk] = v;
    }
#pragma unroll
    for (int j = 0; j < 8; ++j) {
      int idx = t + 256 * j;
      int kk = idx >> 7, oo = idx & 127;
      int kg = kc + kk;
      Bs[kk][oo] = (kg < 128) ? W1l[oo * 128 + kg] : W1r[oo * 128 + (kg - 128)];
    }
    __syncthreads();
#pragma unroll
    for (int kk = 0; kk < 16; ++kk) {
      float av[4], bv[8];
#pragma unroll
      for (int a = 0; a < 4; ++a) av[a] = As[ty + 16 * a][kk];
#pragma unroll
      for (int b = 0; b < 8; ++b) bv[b] = Bs[kk][tx + 16 * b];
#pragma unroll
      for (int a = 0; a < 4; ++a)
#pragma unroll
        for (int b = 0; b < 8; ++b) acc[a][b] += av[a] * bv[b];
    }
    __syncthreads();
  }
  // bias + relu -> LDS h1 tile
#pragma unroll
  for (int a = 0; a < 4; ++a)
#pragma unroll
    for (int b = 0; b < 8; ++b) {
      int n = ty + 16 * a, o = tx + 16 * b;
      hs[n][o] = fmaxf(acc[a][b] + b1[o], 0.f);
    }
  __syncthreads();
  // project h1 tile to p (W2l) and r (W2r): 64 nodes x 8 outputs, 2/thread
#pragma unroll
  for (int uu = 0; uu < 2; ++uu) {
    int u = 2 * t + uu;
    int n = u >> 3, po = u & 7;
    int row = node0 + n;
    if (row < NN) {
      const float* w = (po < 4) ? (W2l + po * 128) : (W2r + (po - 4) * 128);
      float s = 0.f;
#pragma unroll
      for (int k = 0; k < 128; ++k) s += hs[n][k] * w[k];
      if (po < 4) p[row * 4 + po] = s;
      else        r[row * 4 + (po - 4)] = s;
    }
  }
}

// ---------------- layer-2 aggregation (4-wide) + final linear ----------------
__global__ void k_final(const float* __restrict__ p, const float* __restrict__ r,
                        const int* __restrict__ csr, const int* __restrict__ off,
                        const int* __restrict__ deg,
                        const float* __restrict__ b2,
                        const float* __restrict__ Wlin, const float* __restrict__ blin,
                        float* __restrict__ out) {
  int i = blockIdx.x * blockDim.x + threadIdx.x;
  if (i >= NN) return;
  int cnt = deg[i], st = off[i];
  float a0 = 0.f, a1 = 0.f, a2 = 0.f, a3 = 0.f;
  for (int e = 0; e < cnt; ++e) {
    int s = csr[st + e];
    const float4 pv = *(const float4*)(p + s * 4);
    a0 += pv.x; a1 += pv.y; a2 += pv.z; a3 += pv.w;
  }
  float inv = 1.f / (float)max(cnt, 1);
  float4 rv = *(const float4*)(r + i * 4);
  float g0 = a0 * inv + b2[0] + rv.x;
  float g1 = a1 * inv + b2[1] + rv.y;
  float g2 = a2 * inv + b2[2] + rv.z;
  float g3 = a3 * inv + b2[3] + rv.w;
  float o0 = g0 * Wlin[0] + g1 * Wlin[1] + g2 * Wlin[2] + g3 * Wlin[3] + blin[0];
  float o1 = g0 * Wlin[4] + g1 * Wlin[5] + g2 * Wlin[6] + g3 * Wlin[7] + blin[1];
  out[i * 2 + 0] = o0;
  out[i * 2 + 1] = o1;
}

// ---------------- launch ----------------

extern "C" void kernel_launch(void* const* d_in, const int* in_sizes, int n_in,
                              void* d_out, int out_size, void* d_ws, size_t ws_size,
                              hipStream_t stream) {
  const float* x    = (const float*)d_in[0];
  const int*   ei   = (const int*)d_in[1];
  const int*   src  = ei;
  const int*   dst  = ei + NE;
  const float* W1l  = (const float*)d_in[2];
  const float* b1   = (const float*)d_in[3];
  const float* W1r  = (const float*)d_in[4];
  const float* W2l  = (const float*)d_in[5];
  const float* b2   = (const float*)d_in[6];
  const float* W2r  = (const float*)d_in[7];
  const float* Wlin = (const float*)d_in[8];
  const float* blin = (const float*)d_in[9];
  float* out = (float*)d_out;

  char* w = (char*)d_ws;
  size_t o = 0;
  auto alloc = [&](size_t bytes) {
    void* pp = (void*)(w + o);
    o = (o + bytes + 255) & ~(size_t)255;
    return pp;
  };
  int*   deg   = (int*)alloc(NN * 4);
  int*   offs  = (int*)alloc(NN * 4);
  int*   cur   = (int*)alloc(NN * 4);
  int*   bsum  = (int*)alloc(128 * 4);
  int*   bpref = (int*)alloc(128 * 4);
  int*   csr   = (int*)alloc((size_t)NE * 4);
  float* aggb  = (float*)alloc((size_t)NN * 128 * 4);
  float* pbuf  = (float*)alloc((size_t)NN * 4 * 4);
  float* rbuf  = (float*)alloc((size_t)NN * 4 * 4);

  const int NB = (NN + 1023) / 1024;  // 98 chunks

  hipLaunchKernelGGL(k_zero,  dim3((NN + 255) / 256), dim3(256), 0, stream, deg);
  hipLaunchKernelGGL(k_count, dim3((NE + 255) / 256), dim3(256), 0, stream, dst, deg);
  hipLaunchKernelGGL(k_scan1, dim3(NB), dim3(256), 0, stream, deg, bsum);
  hipLaunchKernelGGL(k_scan2, dim3(1), dim3(64), 0, stream, bsum, bpref, NB);
  hipLaunchKernelGGL(k_scan3, dim3(NB), dim3(256), 0, stream, deg, bpref, offs, cur);
  hipLaunchKernelGGL(k_fill,  dim3((NE + 255) / 256), dim3(256), 0, stream, src, dst, cur, csr);
  hipLaunchKernelGGL(k_agg1,  dim3(NN), dim3(128), 0, stream, x, csr, offs, deg, aggb);
  hipLaunchKernelGGL(k_gemm1, dim3((NN + 63) / 64), dim3(256), 0, stream,
                     aggb, x, W1l, W1r, b1, W2l, W2r, pbuf, rbuf);
  hipLaunchKernelGGL(k_final, dim3((NN + 255) / 256), dim3(256), 0, stream,
                     pbuf, rbuf, csr, offs, deg, b2, Wlin, blin, out);
}

// Round 2
// 495.321 us; speedup vs baseline: 1.8091x; 1.8091x over previous
//
#include <hip/hip_runtime.h>

#define NN 100000
#define NE 1600000
#define FEAT 128

typedef __attribute__((ext_vector_type(8))) short v8s;
typedef __attribute__((ext_vector_type(4))) float v4f;

__device__ __forceinline__ unsigned short f2bf(float f) {
  unsigned int u = __float_as_uint(f);
  unsigned int r = (u + 0x7FFFu + ((u >> 16) & 1u)) >> 16;
  return (unsigned short)r;
}
__device__ __forceinline__ float bflo(unsigned int w) { return __uint_as_float(w << 16); }
__device__ __forceinline__ float bfhi(unsigned int w) { return __uint_as_float(w & 0xFFFF0000u); }

// ---------------- CSR build ----------------

__global__ void k_zero(int* __restrict__ deg) {
  int i = blockIdx.x * blockDim.x + threadIdx.x;
  if (i < NN) deg[i] = 0;
}

__global__ void k_count(const int* __restrict__ dst, int* __restrict__ deg) {
  int e = blockIdx.x * blockDim.x + threadIdx.x;
  if (e < NE) atomicAdd(&deg[dst[e]], 1);
}

__global__ void k_scan1(const int* __restrict__ deg, int* __restrict__ bsum) {
  __shared__ int red[4];
  int b = blockIdx.x, t = threadIdx.x;
  int s = 0;
  for (int j = 0; j < 4; ++j) {
    int i = b * 1024 + t + 256 * j;
    if (i < NN) s += deg[i];
  }
  for (int o = 32; o > 0; o >>= 1) s += __shfl_down(s, o, 64);
  if ((t & 63) == 0) red[t >> 6] = s;
  __syncthreads();
  if (t == 0) bsum[b] = red[0] + red[1] + red[2] + red[3];
}

__global__ void k_scan2(const int* __restrict__ bsum, int* __restrict__ bpref, int nb) {
  if (threadIdx.x == 0) {
    int run = 0;
    for (int b = 0; b < nb; ++b) { bpref[b] = run; run += bsum[b]; }
  }
}

__global__ void k_scan3(const int* __restrict__ deg, const int* __restrict__ bpref,
                        int* __restrict__ off, int* __restrict__ cur) {
  __shared__ int sc[256];
  int b = blockIdx.x, t = threadIdx.x;
  int base = b * 1024 + t * 4;
  int d[4]; int s = 0;
  for (int j = 0; j < 4; ++j) {
    int i = base + j;
    d[j] = (i < NN) ? deg[i] : 0;
    s += d[j];
  }
  sc[t] = s;
  __syncthreads();
  for (int o = 1; o < 256; o <<= 1) {
    int v = (t >= o) ? sc[t - o] : 0;
    __syncthreads();
    sc[t] += v;
    __syncthreads();
  }
  int run = bpref[b] + sc[t] - s;
  for (int j = 0; j < 4; ++j) {
    int i = base + j;
    if (i < NN) { off[i] = run; cur[i] = run; }
    run += d[j];
  }
}

__global__ void k_fill(const int* __restrict__ src, const int* __restrict__ dst,
                       int* __restrict__ cur, int* __restrict__ csr) {
  int e = blockIdx.x * blockDim.x + threadIdx.x;
  if (e < NE) {
    int pos = atomicAdd(&cur[dst[e]], 1);
    csr[pos] = src[e];
  }
}

// ---------------- fp32 -> bf16 casts ----------------

__global__ void k_cast(const float* __restrict__ x, unsigned short* __restrict__ xb) {
  int i = blockIdx.x * blockDim.x + threadIdx.x;  // 4 elems per thread
  const float4 f = ((const float4*)x)[i];
  ushort4 o;
  o.x = f2bf(f.x); o.y = f2bf(f.y); o.z = f2bf(f.z); o.w = f2bf(f.w);
  ((ushort4*)xb)[i] = o;
}

__global__ void k_packw(const float* __restrict__ W1l, const float* __restrict__ W1r,
                        unsigned short* __restrict__ Wcat) {
  int i = blockIdx.x * blockDim.x + threadIdx.x;  // 0..32767
  float f = (i < 16384) ? W1l[i] : W1r[i - 16384];
  Wcat[i] = f2bf(f);
}

// ---------------- MFMA GEMM: u = x@W1l^T (bf16), v = x@W1r^T (bf16) --------
// Wcat rows 0..127 = W1l, rows 128..255 = W1r. Each wave: 16 rows x 256 cols,
// K=128. Fragments loaded directly from global (no LDS, no barriers).
__global__ __launch_bounds__(256) void k_gemm1(
    const unsigned short* __restrict__ xb, const unsigned short* __restrict__ Wcat,
    unsigned short* __restrict__ u, unsigned short* __restrict__ v) {
  int wave = threadIdx.x >> 6, l = threadIdx.x & 63;
  int m0 = blockIdx.x * 64 + wave * 16;
  if (m0 >= NN) return;
  int lr = l & 15;       // row/col-within-tile index
  int kq = l >> 4;       // k-quad
  int rowc = min(m0 + lr, NN - 1);

  // A fragments: lane holds A[m=l&15][k = kq*8 + j], 4 k-steps of 32
  v8s a[4];
#pragma unroll
  for (int ks = 0; ks < 4; ++ks)
    a[ks] = *(const v8s*)(xb + (size_t)rowc * 128 + ks * 32 + kq * 8);

  v4f acc[16];
#pragma unroll
  for (int nt = 0; nt < 16; ++nt) acc[nt] = (v4f){0.f, 0.f, 0.f, 0.f};

#pragma unroll
  for (int nt = 0; nt < 16; ++nt) {
    const unsigned short* wrow = Wcat + (size_t)(nt * 16 + lr) * 128;
#pragma unroll
    for (int ks = 0; ks < 4; ++ks) {
      v8s b = *(const v8s*)(wrow + ks * 32 + kq * 8);
      acc[nt] = __builtin_amdgcn_mfma_f32_16x16x32_bf16(a[ks], b, acc[nt], 0, 0, 0);
    }
  }

  // C layout: lane holds C[row=(l>>4)*4+rr][col=l&15] per 16x16 tile
#pragma unroll
  for (int nt = 0; nt < 16; ++nt) {
#pragma unroll
    for (int rr = 0; rr < 4; ++rr) {
      int mrow = m0 + kq * 4 + rr;
      if (mrow < NN) {
        unsigned short bv = f2bf(acc[nt][rr]);
        int col = nt * 16 + lr;
        if (nt < 8) u[(size_t)mrow * 128 + col] = bv;
        else        v[(size_t)mrow * 128 + (col - 128)] = bv;
      }
    }
  }
}

// ---------------- fused: mean-agg(u) + v + b1 -> relu -> h1; p=h1@W2l^T,
//                  r=h1@W2r^T. One wave per node; lane covers dims 2l,2l+1.
__global__ __launch_bounds__(256) void k_agg(
    const unsigned short* __restrict__ u, const unsigned short* __restrict__ v,
    const int* __restrict__ csr, const int* __restrict__ off, const int* __restrict__ deg,
    const float* __restrict__ b1,
    const float* __restrict__ W2l, const float* __restrict__ W2r,
    float* __restrict__ p, float* __restrict__ r) {
  int wid = (blockIdx.x * blockDim.x + threadIdx.x) >> 6;  // node
  int l = threadIdx.x & 63;
  if (wid >= NN) return;
  int cnt = deg[wid], st = off[wid];
  const unsigned int* ub = (const unsigned int*)u;

  float a0 = 0.f, a1 = 0.f;
  int e = 0;
  for (; e + 4 <= cnt; e += 4) {
    int s0 = csr[st + e], s1 = csr[st + e + 1], s2 = csr[st + e + 2], s3 = csr[st + e + 3];
    unsigned int w0 = ub[(size_t)s0 * 64 + l];
    unsigned int w1 = ub[(size_t)s1 * 64 + l];
    unsigned int w2 = ub[(size_t)s2 * 64 + l];
    unsigned int w3 = ub[(size_t)s3 * 64 + l];
    a0 += bflo(w0) + bflo(w1) + bflo(w2) + bflo(w3);
    a1 += bfhi(w0) + bfhi(w1) + bfhi(w2) + bfhi(w3);
  }
  for (; e < cnt; ++e) {
    unsigned int w = ub[(size_t)csr[st + e] * 64 + l];
    a0 += bflo(w); a1 += bfhi(w);
  }
  float inv = 1.f / (float)max(cnt, 1);
  unsigned int vw = ((const unsigned int*)v)[(size_t)wid * 64 + l];
  float2 bb = *(const float2*)(b1 + 2 * l);
  float h0 = fmaxf(a0 * inv + bflo(vw) + bb.x, 0.f);
  float h1 = fmaxf(a1 * inv + bfhi(vw) + bb.y, 0.f);

  // 8 outputs: p[0..3] via W2l, r[0..3] via W2r
#pragma unroll
  for (int o = 0; o < 8; ++o) {
    const float* wr = (o < 4) ? (W2l + o * 128) : (W2r + (o - 4) * 128);
    float2 wv = *(const float2*)(wr + 2 * l);
    float s = h0 * wv.x + h1 * wv.y;
#pragma unroll
    for (int d = 32; d > 0; d >>= 1) s += __shfl_xor(s, d, 64);
    if (l == o) {
      if (o < 4) p[(size_t)wid * 4 + o] = s;
      else       r[(size_t)wid * 4 + (o - 4)] = s;
    }
  }
}

// ---------------- layer-2 aggregation (4-wide) + final linear ----------------
__global__ void k_final(const float* __restrict__ p, const float* __restrict__ r,
                        const int* __restrict__ csr, const int* __restrict__ off,
                        const int* __restrict__ deg,
                        const float* __restrict__ b2,
                        const float* __restrict__ Wlin, const float* __restrict__ blin,
                        float* __restrict__ out) {
  int i = blockIdx.x * blockDim.x + threadIdx.x;
  if (i >= NN) return;
  int cnt = deg[i], st = off[i];
  float a0 = 0.f, a1 = 0.f, a2 = 0.f, a3 = 0.f;
  for (int e = 0; e < cnt; ++e) {
    int s = csr[st + e];
    const float4 pv = *(const float4*)(p + (size_t)s * 4);
    a0 += pv.x; a1 += pv.y; a2 += pv.z; a3 += pv.w;
  }
  float inv = 1.f / (float)max(cnt, 1);
  float4 rv = *(const float4*)(r + (size_t)i * 4);
  float g0 = a0 * inv + b2[0] + rv.x;
  float g1 = a1 * inv + b2[1] + rv.y;
  float g2 = a2 * inv + b2[2] + rv.z;
  float g3 = a3 * inv + b2[3] + rv.w;
  out[(size_t)i * 2 + 0] = g0 * Wlin[0] + g1 * Wlin[1] + g2 * Wlin[2] + g3 * Wlin[3] + blin[0];
  out[(size_t)i * 2 + 1] = g0 * Wlin[4] + g1 * Wlin[5] + g2 * Wlin[6] + g3 * Wlin[7] + blin[1];
}

// ---------------- launch ----------------

extern "C" void kernel_launch(void* const* d_in, const int* in_sizes, int n_in,
                              void* d_out, int out_size, void* d_ws, size_t ws_size,
                              hipStream_t stream) {
  const float* x    = (const float*)d_in[0];
  const int*   ei   = (const int*)d_in[1];
  const int*   src  = ei;
  const int*   dst  = ei + NE;
  const float* W1l  = (const float*)d_in[2];
  const float* b1   = (const float*)d_in[3];
  const float* W1r  = (const float*)d_in[4];
  const float* W2l  = (const float*)d_in[5];
  const float* b2   = (const float*)d_in[6];
  const float* W2r  = (const float*)d_in[7];
  const float* Wlin = (const float*)d_in[8];
  const float* blin = (const float*)d_in[9];
  float* out = (float*)d_out;

  char* w = (char*)d_ws;
  size_t o = 0;
  auto alloc = [&](size_t bytes) {
    void* pp = (void*)(w + o);
    o = (o + bytes + 255) & ~(size_t)255;
    return pp;
  };
  int*   deg   = (int*)alloc(NN * 4);
  int*   offs  = (int*)alloc(NN * 4);
  int*   cur   = (int*)alloc(NN * 4);
  int*   bsum  = (int*)alloc(128 * 4);
  int*   bpref = (int*)alloc(128 * 4);
  int*   csr   = (int*)alloc((size_t)NE * 4);
  unsigned short* xb   = (unsigned short*)alloc((size_t)NN * 128 * 2);
  unsigned short* Wcat = (unsigned short*)alloc(256 * 128 * 2);
  unsigned short* ubuf = (unsigned short*)alloc((size_t)NN * 128 * 2);
  unsigned short* vbuf = (unsigned short*)alloc((size_t)NN * 128 * 2);
  float* pbuf  = (float*)alloc((size_t)NN * 4 * 4);
  float* rbuf  = (float*)alloc((size_t)NN * 4 * 4);

  const int NB = (NN + 1023) / 1024;  // 98 chunks

  hipLaunchKernelGGL(k_zero,  dim3((NN + 255) / 256), dim3(256), 0, stream, deg);
  hipLaunchKernelGGL(k_count, dim3((NE + 255) / 256), dim3(256), 0, stream, dst, deg);
  hipLaunchKernelGGL(k_scan1, dim3(NB), dim3(256), 0, stream, deg, bsum);
  hipLaunchKernelGGL(k_scan2, dim3(1), dim3(64), 0, stream, bsum, bpref, NB);
  hipLaunchKernelGGL(k_scan3, dim3(NB), dim3(256), 0, stream, deg, bpref, offs, cur);
  hipLaunchKernelGGL(k_fill,  dim3((NE + 255) / 256), dim3(256), 0, stream, src, dst, cur, csr);
  hipLaunchKernelGGL(k_cast,  dim3((NN * 128 / 4 + 255) / 256), dim3(256), 0, stream, x, xb);
  hipLaunchKernelGGL(k_packw, dim3(128), dim3(256), 0, stream, W1l, W1r, Wcat);
  hipLaunchKernelGGL(k_gemm1, dim3((NN + 63) / 64), dim3(256), 0, stream, xb, Wcat, ubuf, vbuf);
  hipLaunchKernelGGL(k_agg,   dim3((NN * 64 + 255) / 256), dim3(256), 0, stream,
                     ubuf, vbuf, csr, offs, deg, b1, W2l, W2r, pbuf, rbuf);
  hipLaunchKernelGGL(k_final, dim3((NN + 255) / 256), dim3(256), 0, stream,
                     pbuf, rbuf, csr, offs, deg, b2, Wlin, blin, out);
}